// Round 1
// baseline (808.239 us; speedup 1.0000x reference)
//
#include <hip/hip_runtime.h>
#include <hip/hip_cooperative_groups.h>
#include <math.h>

namespace cg = cooperative_groups;

#define NBLK 256
#define DD 128
#define SMAX 2048

__device__ __forceinline__ float sigmoidf(float x) { return 1.0f / (1.0f + expf(-x)); }

// ---------------------------------------------------------------------------
// Schedule kernel: dependency levels via last-conflicting-predecessor + fixpoint
// ---------------------------------------------------------------------------
__global__ __launch_bounds__(1024) void schedule_kernel(
    const int* __restrict__ heads, const int* __restrict__ tails, int S,
    int* __restrict__ order, int* __restrict__ level_off, int* __restrict__ n_levels) {
  __shared__ int sh[SMAX], st[SMAX], lvl[SMAX], ph[SMAX], pt[SMAX], cnt[SMAX];
  __shared__ int changed, maxl;
  const int tid = threadIdx.x;

  for (int j = tid; j < S; j += 1024) { sh[j] = heads[j]; st[j] = tails[j]; }
  __syncthreads();

  // Predecessors. j1 in [0,1024), j2 in [1024,2048) -> balanced total work.
  for (int r = 0; r < 2; ++r) {
    int j = (r == 0) ? tid : (2047 - tid);
    if (j < S && (r == 0 ? (tid < 1024) : (2047 - tid >= 1024))) {
      int myh = sh[j], myt = st[j];
      int mph = -1, mpt = -1;
      for (int i = 0; i < j; ++i) {
        int a = sh[i], b = st[i];
        if (a == myh || b == myh) mph = i;
        if (a == myt || b == myt) mpt = i;
      }
      ph[j] = mph; pt[j] = mpt; lvl[j] = 1;
    }
  }
  __syncthreads();

  // Fixpoint relaxation of levels (monotone, converges in <= depth passes).
  for (int it = 0; it < S + 2; ++it) {
    __syncthreads();
    if (tid == 0) changed = 0;
    __syncthreads();
    for (int j = tid; j < S; j += 1024) {
      int l = 1;
      int a = ph[j]; if (a >= 0) l = lvl[a] + 1;
      int b = pt[j]; if (b >= 0) { int lb = lvl[b] + 1; if (lb > l) l = lb; }
      if (l != lvl[j]) { lvl[j] = l; changed = 1; }
    }
    __syncthreads();
    if (!changed) break;
  }

  // Max level.
  if (tid == 0) maxl = 0;
  __syncthreads();
  for (int j = tid; j < S; j += 1024) atomicMax(&maxl, lvl[j]);
  __syncthreads();
  const int M = maxl;

  // Counts -> offsets.
  for (int l = tid; l < M; l += 1024) cnt[l] = 0;
  __syncthreads();
  for (int j = tid; j < S; j += 1024) atomicAdd(&cnt[lvl[j] - 1], 1);
  __syncthreads();
  if (tid == 0) {
    int run = 0;
    level_off[0] = 0;
    for (int l = 0; l < M; ++l) { run += cnt[l]; level_off[l + 1] = run; }
    n_levels[0] = M;
  }
  __syncthreads();

  // Place step ids bucketed by level.
  for (int l = tid; l < M; l += 1024) cnt[l] = 0;
  __syncthreads();
  for (int j = tid; j < S; j += 1024) {
    int lv = lvl[j] - 1;
    int pos = level_off[lv] + atomicAdd(&cnt[lv], 1);
    order[pos] = j;
  }
}

// ---------------------------------------------------------------------------
// Process kernel: cooperative, one block per step, grid.sync() between levels
// ---------------------------------------------------------------------------
struct PParams {
  const int* heads; const int* tails; const float* times;
  float* node_rep; float* cell_head; float* hidden_head; float* cell_tail; float* hidden_tail;
  const float* Weh1; const float* Weh2; const float* beh;
  const float* Wet1; const float* Wet2; const float* bet;
  const float* Wxh; const float* Whh; const float* bh; const float* Wdh; const float* bdh;
  const float* Wxt; const float* Wht; const float* bt; const float* Wdt; const float* bdt;
  const float* Wc1; const float* Wc2;
  float* out; float* rt;
  const int* order; const int* level_off; const int* n_levels;
  int S;
};

__global__ __launch_bounds__(256) void process_kernel(PParams p) {
  cg::grid_group grid = cg::this_grid();
  const int tid = threadIdx.x;

  __shared__ float repH[DD], repT[DD], cHs[DD], hHs[DD], cTs[DD], hTs[DD];
  __shared__ float htH[DD], hhT[DD];              // old ht[h], old hh[t]
  __shared__ float edgeH[DD], edgeT[DD], cadjH[DD], cadjT[DD];
  __shared__ float zH[512], zT[512];
  __shared__ float nhH[DD], nhT[DD];              // new hidden head/tail
  __shared__ float dec2[2], tmS;
  __shared__ int idx2[2];

  const int nlv = p.n_levels[0];
  for (int lv = 0; lv < nlv; ++lv) {
    const int beg = p.level_off[lv], end = p.level_off[lv + 1];
    for (int k = beg + blockIdx.x; k < end; k += gridDim.x) {
      __syncthreads();  // protect idx2/LDS from previous step's readers
      const int s = p.order[k];
      if (tid == 0) { idx2[0] = p.heads[s]; idx2[1] = p.tails[s]; tmS = p.times[s]; }
      __syncthreads();
      const int hI = idx2[0], tI = idx2[1];
      const float tm = tmS;
      if (tid < 2) dec2[tid] = expf(-(tm - p.rt[idx2[tid]]));

      // Gather (pre-update values) + emit outputs
      if (tid < DD) {
        const int d = tid;
        const size_t o = (size_t)hI * DD + d;
        float r = p.node_rep[o];
        repH[d] = r; cHs[d] = p.cell_head[o]; hHs[d] = p.hidden_head[o];
        htH[d] = p.hidden_tail[o];
        p.out[(size_t)s * DD + d] = r;
      } else {
        const int d = tid - DD;
        const size_t o = (size_t)tI * DD + d;
        float r = p.node_rep[o];
        repT[d] = r; cTs[d] = p.cell_tail[o]; hTs[d] = p.hidden_tail[o];
        hhT[d] = p.hidden_head[o];
        p.out[(size_t)(p.S + s) * DD + d] = r;
      }
      __syncthreads();

      // Phase A: edge pre-activations + short-term-memory decay adjust
      if (tid < DD) {
        const int e = tid;
        float ae = p.beh[e], ac = p.bdh[e];
#pragma unroll 4
        for (int d = 0; d < DD; ++d) {
          ae += repH[d] * p.Weh1[d * DD + e] + repT[d] * p.Weh2[d * DD + e];
          ac += cHs[d] * p.Wdh[d * DD + e];
        }
        edgeH[e] = tanhf(ae);
        float cs = tanhf(ac);
        cadjH[e] = cHs[e] - cs + cs * dec2[0];
      } else {
        const int e = tid - DD;
        float ae = p.bet[e], ac = p.bdt[e];
#pragma unroll 4
        for (int d = 0; d < DD; ++d) {
          ae += repH[d] * p.Wet1[d * DD + e] + repT[d] * p.Wet2[d * DD + e];
          ac += cTs[d] * p.Wdt[d * DD + e];
        }
        edgeT[e] = tanhf(ae);
        float cs = tanhf(ac);
        cadjT[e] = cTs[e] - cs + cs * dec2[1];
      }
      __syncthreads();

      // Phase B: gate pre-activations z = x@Wx + h@Wh + b  (4 outputs/thread)
      {
        float a0 = p.bh[tid], a1 = p.bh[tid + 256];
        float b0 = p.bt[tid], b1 = p.bt[tid + 256];
#pragma unroll 2
        for (int d = 0; d < DD; ++d) {
          const float eh = edgeH[d], hh = hHs[d], et = edgeT[d], ht = hTs[d];
          a0 += eh * p.Wxh[d * 512 + tid]       + hh * p.Whh[d * 512 + tid];
          a1 += eh * p.Wxh[d * 512 + tid + 256] + hh * p.Whh[d * 512 + tid + 256];
          b0 += et * p.Wxt[d * 512 + tid]       + ht * p.Wht[d * 512 + tid];
          b1 += et * p.Wxt[d * 512 + tid + 256] + ht * p.Wht[d * 512 + tid + 256];
        }
        zH[tid] = a0; zH[tid + 256] = a1;
        zT[tid] = b0; zT[tid + 256] = b1;
      }
      __syncthreads();

      // Phase C: gates, new cell/hidden, scatter cell/hidden/rt
      if (tid < DD) {
        const int e = tid;
        float ig = sigmoidf(zH[e]), fg = sigmoidf(zH[DD + e]);
        float og = sigmoidf(zH[256 + e]), gg = tanhf(zH[384 + e]);
        float c = fg * cadjH[e] + ig * gg;
        float h = og * tanhf(c);
        nhH[e] = h;
        p.cell_head[(size_t)hI * DD + e] = c;
        p.hidden_head[(size_t)hI * DD + e] = h;
      } else {
        const int e = tid - DD;
        float ig = sigmoidf(zT[e]), fg = sigmoidf(zT[DD + e]);
        float og = sigmoidf(zT[256 + e]), gg = tanhf(zT[384 + e]);
        float c = fg * cadjT[e] + ig * gg;
        float h = og * tanhf(c);
        nhT[e] = h;
        p.cell_tail[(size_t)tI * DD + e] = c;
        p.hidden_tail[(size_t)tI * DD + e] = h;
      }
      if (tid == 0) p.rt[hI] = tm;
      if (tid == 1) p.rt[tI] = tm;
      __syncthreads();

      // Phase D: combiner + rep scatter (tail wins on h==t, matching reference)
      if (tid < DD) {
        const int e = tid;
        float a = 0.f;
#pragma unroll 4
        for (int d = 0; d < DD; ++d)
          a += nhH[d] * p.Wc1[d * DD + e] + htH[d] * p.Wc2[d * DD + e];
        if (hI != tI) p.node_rep[(size_t)hI * DD + e] = tanhf(a);
      } else {
        const int e = tid - DD;
        float a = 0.f;
#pragma unroll 4
        for (int d = 0; d < DD; ++d)
          a += hhT[d] * p.Wc1[d * DD + e] + nhT[d] * p.Wc2[d * DD + e];
        p.node_rep[(size_t)tI * DD + e] = tanhf(a);
      }
    }
    __threadfence();
    grid.sync();
  }
}

// ---------------------------------------------------------------------------
extern "C" void kernel_launch(void* const* d_in, const int* in_sizes, int n_in,
                              void* d_out, int out_size, void* d_ws, size_t ws_size,
                              hipStream_t stream) {
  const int* heads = (const int*)d_in[0];
  const int* tails = (const int*)d_in[1];
  const float* times = (const float*)d_in[2];
  float* node_rep    = (float*)d_in[3];
  float* cell_head   = (float*)d_in[4];
  float* hidden_head = (float*)d_in[5];
  float* cell_tail   = (float*)d_in[6];
  float* hidden_tail = (float*)d_in[7];
  const float* Weh1 = (const float*)d_in[8];
  const float* Weh2 = (const float*)d_in[9];
  const float* beh  = (const float*)d_in[10];
  const float* Wet1 = (const float*)d_in[11];
  const float* Wet2 = (const float*)d_in[12];
  const float* bet  = (const float*)d_in[13];
  const float* Wxh  = (const float*)d_in[14];
  const float* Whh  = (const float*)d_in[15];
  const float* bh   = (const float*)d_in[16];
  const float* Wdh  = (const float*)d_in[17];
  const float* bdh  = (const float*)d_in[18];
  const float* Wxt  = (const float*)d_in[19];
  const float* Wht  = (const float*)d_in[20];
  const float* bt   = (const float*)d_in[21];
  const float* Wdt  = (const float*)d_in[22];
  const float* bdt  = (const float*)d_in[23];
  const float* Wc1  = (const float*)d_in[24];
  const float* Wc2  = (const float*)d_in[25];

  const int S = in_sizes[0];
  const int N = in_sizes[3] / DD;

  char* ws = (char*)d_ws;
  float* rt = (float*)ws;
  size_t rtBytes = (((size_t)N * 4) + 511) & ~(size_t)511;
  int* order     = (int*)(ws + rtBytes);
  int* level_off = order + SMAX;
  int* n_levels  = level_off + SMAX + 1;

  hipMemsetAsync(rt, 0, (size_t)N * 4, stream);
  schedule_kernel<<<1, 1024, 0, stream>>>(heads, tails, S, order, level_off, n_levels);

  PParams p;
  p.heads = heads; p.tails = tails; p.times = times;
  p.node_rep = node_rep; p.cell_head = cell_head; p.hidden_head = hidden_head;
  p.cell_tail = cell_tail; p.hidden_tail = hidden_tail;
  p.Weh1 = Weh1; p.Weh2 = Weh2; p.beh = beh;
  p.Wet1 = Wet1; p.Wet2 = Wet2; p.bet = bet;
  p.Wxh = Wxh; p.Whh = Whh; p.bh = bh; p.Wdh = Wdh; p.bdh = bdh;
  p.Wxt = Wxt; p.Wht = Wht; p.bt = bt; p.Wdt = Wdt; p.bdt = bdt;
  p.Wc1 = Wc1; p.Wc2 = Wc2;
  p.out = (float*)d_out; p.rt = rt;
  p.order = order; p.level_off = level_off; p.n_levels = n_levels;
  p.S = S;

  void* args[] = { (void*)&p };
  hipLaunchCooperativeKernel((const void*)process_kernel, dim3(NBLK), dim3(256),
                             args, 0, stream);
}

// Round 3
// 779.032 us; speedup vs baseline: 1.0375x; 1.0375x over previous
//
#include <hip/hip_runtime.h>
#include <hip/hip_cooperative_groups.h>
#include <math.h>

namespace cg = cooperative_groups;

#define NBLK_MAX 1024      // desired: 4 blocks/CU -> 16 waves/CU
#define DD 128
#define SMAX 2048

__device__ __forceinline__ float sigmoidf(float x) { return 1.0f / (1.0f + expf(-x)); }

// ---------------------------------------------------------------------------
// Predecessor kernel: block j scans i<j for last step sharing a node.
// O(S^2) total but spread over S blocks x 64 lanes: <=32 iters/lane.
// ---------------------------------------------------------------------------
__global__ __launch_bounds__(64) void pred_kernel(
    const int* __restrict__ heads, const int* __restrict__ tails, int S,
    int* __restrict__ ph, int* __restrict__ pt) {
  const int j = blockIdx.x;
  if (j >= S) return;
  const int myh = heads[j], myt = tails[j];
  const int lane = threadIdx.x;
  int mph = -1, mpt = -1;
  for (int i = lane; i < j; i += 64) {
    int a = heads[i], b = tails[i];
    if (a == myh || b == myh) mph = i;
    if (a == myt || b == myt) mpt = i;
  }
#pragma unroll
  for (int off = 32; off > 0; off >>= 1) {
    mph = max(mph, __shfl_down(mph, off));
    mpt = max(mpt, __shfl_down(mpt, off));
  }
  if (lane == 0) { ph[j] = mph; pt[j] = mpt; }
}

// ---------------------------------------------------------------------------
// Finalize: fixpoint level relaxation (depth ~4-8 passes) + bucket by level.
// ---------------------------------------------------------------------------
__global__ __launch_bounds__(1024) void finalize_kernel(
    int S, const int* __restrict__ phg, const int* __restrict__ ptg,
    int* __restrict__ order, int* __restrict__ level_off, int* __restrict__ n_levels) {
  __shared__ int lvl[SMAX], ph[SMAX], pt[SMAX], cnt[SMAX];
  __shared__ int changed, maxl;
  const int tid = threadIdx.x;

  for (int j = tid; j < S; j += 1024) { ph[j] = phg[j]; pt[j] = ptg[j]; lvl[j] = 1; }
  __syncthreads();

  for (int it = 0; it < S + 2; ++it) {
    if (tid == 0) changed = 0;
    __syncthreads();
    for (int j = tid; j < S; j += 1024) {
      int l = 1;
      int a = ph[j]; if (a >= 0) l = lvl[a] + 1;
      int b = pt[j]; if (b >= 0) { int lb = lvl[b] + 1; if (lb > l) l = lb; }
      if (l != lvl[j]) { lvl[j] = l; changed = 1; }
    }
    __syncthreads();
    if (!changed) break;
    __syncthreads();
  }

  if (tid == 0) maxl = 0;
  __syncthreads();
  for (int j = tid; j < S; j += 1024) atomicMax(&maxl, lvl[j]);
  __syncthreads();
  const int M = maxl;

  for (int l = tid; l < M; l += 1024) cnt[l] = 0;
  __syncthreads();
  for (int j = tid; j < S; j += 1024) atomicAdd(&cnt[lvl[j] - 1], 1);
  __syncthreads();
  if (tid == 0) {
    int run = 0;
    level_off[0] = 0;
    for (int l = 0; l < M; ++l) { run += cnt[l]; level_off[l + 1] = run; }
    n_levels[0] = M;
  }
  __syncthreads();

  for (int l = tid; l < M; l += 1024) cnt[l] = 0;
  __syncthreads();
  for (int j = tid; j < S; j += 1024) {
    int lv = lvl[j] - 1;
    int pos = level_off[lv] + atomicAdd(&cnt[lv], 1);
    order[pos] = j;
  }
}

// ---------------------------------------------------------------------------
// Process kernel: cooperative, one block per step, grid.sync() between levels
// ---------------------------------------------------------------------------
struct PParams {
  const int* heads; const int* tails; const float* times;
  float* node_rep; float* cell_head; float* hidden_head; float* cell_tail; float* hidden_tail;
  const float* Weh1; const float* Weh2; const float* beh;
  const float* Wet1; const float* Wet2; const float* bet;
  const float* Wxh; const float* Whh; const float* bh; const float* Wdh; const float* bdh;
  const float* Wxt; const float* Wht; const float* bt; const float* Wdt; const float* bdt;
  const float* Wc1; const float* Wc2;
  float* out; float* rt;
  const int* order; const int* level_off; const int* n_levels;
  int S;
};

__global__ __launch_bounds__(256) void process_kernel(PParams p) {
  cg::grid_group grid = cg::this_grid();
  const int tid = threadIdx.x;

  __shared__ float repH[DD], repT[DD], cHs[DD], hHs[DD], cTs[DD], hTs[DD];
  __shared__ float htH[DD], hhT[DD];              // old ht[h], old hh[t]
  __shared__ float edgeH[DD], edgeT[DD], cadjH[DD], cadjT[DD];
  __shared__ float zH[512], zT[512];
  __shared__ float nhH[DD], nhT[DD];              // new hidden head/tail
  __shared__ float dec2[2], tmS;
  __shared__ int idx2[2];

  int nlv = p.n_levels[0];
  if (nlv < 0) nlv = 0;
  if (nlv > SMAX) nlv = SMAX;
  for (int lv = 0; lv < nlv; ++lv) {
    const int beg = p.level_off[lv], end = p.level_off[lv + 1];
    for (int k = beg + blockIdx.x; k < end; k += gridDim.x) {
      __syncthreads();  // protect idx2/LDS from previous step's readers
      const int s = p.order[k];
      if (tid == 0) { idx2[0] = p.heads[s]; idx2[1] = p.tails[s]; tmS = p.times[s]; }
      __syncthreads();
      const int hI = idx2[0], tI = idx2[1];
      const float tm = tmS;
      if (tid < 2) dec2[tid] = expf(-(tm - p.rt[idx2[tid]]));

      // Gather (pre-update values) + emit outputs
      if (tid < DD) {
        const int d = tid;
        const size_t o = (size_t)hI * DD + d;
        float r = p.node_rep[o];
        repH[d] = r; cHs[d] = p.cell_head[o]; hHs[d] = p.hidden_head[o];
        htH[d] = p.hidden_tail[o];
        p.out[(size_t)s * DD + d] = r;
      } else {
        const int d = tid - DD;
        const size_t o = (size_t)tI * DD + d;
        float r = p.node_rep[o];
        repT[d] = r; cTs[d] = p.cell_tail[o]; hTs[d] = p.hidden_tail[o];
        hhT[d] = p.hidden_head[o];
        p.out[(size_t)(p.S + s) * DD + d] = r;
      }
      __syncthreads();

      // Phase A: edge pre-activations + short-term-memory decay adjust
      if (tid < DD) {
        const int e = tid;
        float ae = p.beh[e], ac = p.bdh[e];
#pragma unroll 4
        for (int d = 0; d < DD; ++d) {
          ae += repH[d] * p.Weh1[d * DD + e] + repT[d] * p.Weh2[d * DD + e];
          ac += cHs[d] * p.Wdh[d * DD + e];
        }
        edgeH[e] = tanhf(ae);
        float cs = tanhf(ac);
        cadjH[e] = cHs[e] - cs + cs * dec2[0];
      } else {
        const int e = tid - DD;
        float ae = p.bet[e], ac = p.bdt[e];
#pragma unroll 4
        for (int d = 0; d < DD; ++d) {
          ae += repH[d] * p.Wet1[d * DD + e] + repT[d] * p.Wet2[d * DD + e];
          ac += cTs[d] * p.Wdt[d * DD + e];
        }
        edgeT[e] = tanhf(ae);
        float cs = tanhf(ac);
        cadjT[e] = cTs[e] - cs + cs * dec2[1];
      }
      __syncthreads();

      // Phase B: gate pre-activations z = x@Wx + h@Wh + b  (4 outputs/thread)
      {
        float a0 = p.bh[tid], a1 = p.bh[tid + 256];
        float b0 = p.bt[tid], b1 = p.bt[tid + 256];
#pragma unroll 2
        for (int d = 0; d < DD; ++d) {
          const float eh = edgeH[d], hh = hHs[d], et = edgeT[d], ht = hTs[d];
          a0 += eh * p.Wxh[d * 512 + tid]       + hh * p.Whh[d * 512 + tid];
          a1 += eh * p.Wxh[d * 512 + tid + 256] + hh * p.Whh[d * 512 + tid + 256];
          b0 += et * p.Wxt[d * 512 + tid]       + ht * p.Wht[d * 512 + tid];
          b1 += et * p.Wxt[d * 512 + tid + 256] + ht * p.Wht[d * 512 + tid + 256];
        }
        zH[tid] = a0; zH[tid + 256] = a1;
        zT[tid] = b0; zT[tid + 256] = b1;
      }
      __syncthreads();

      // Phase C: gates, new cell/hidden, scatter cell/hidden/rt
      if (tid < DD) {
        const int e = tid;
        float ig = sigmoidf(zH[e]), fg = sigmoidf(zH[DD + e]);
        float og = sigmoidf(zH[256 + e]), gg = tanhf(zH[384 + e]);
        float c = fg * cadjH[e] + ig * gg;
        float h = og * tanhf(c);
        nhH[e] = h;
        p.cell_head[(size_t)hI * DD + e] = c;
        p.hidden_head[(size_t)hI * DD + e] = h;
      } else {
        const int e = tid - DD;
        float ig = sigmoidf(zT[e]), fg = sigmoidf(zT[DD + e]);
        float og = sigmoidf(zT[256 + e]), gg = tanhf(zT[384 + e]);
        float c = fg * cadjT[e] + ig * gg;
        float h = og * tanhf(c);
        nhT[e] = h;
        p.cell_tail[(size_t)tI * DD + e] = c;
        p.hidden_tail[(size_t)tI * DD + e] = h;
      }
      if (tid == 0) p.rt[hI] = tm;
      if (tid == 1) p.rt[tI] = tm;
      __syncthreads();

      // Phase D: combiner + rep scatter (tail wins on h==t, matching reference)
      if (tid < DD) {
        const int e = tid;
        float a = 0.f;
#pragma unroll 4
        for (int d = 0; d < DD; ++d)
          a += nhH[d] * p.Wc1[d * DD + e] + htH[d] * p.Wc2[d * DD + e];
        if (hI != tI) p.node_rep[(size_t)hI * DD + e] = tanhf(a);
      } else {
        const int e = tid - DD;
        float a = 0.f;
#pragma unroll 4
        for (int d = 0; d < DD; ++d)
          a += hhT[d] * p.Wc1[d * DD + e] + nhT[d] * p.Wc2[d * DD + e];
        p.node_rep[(size_t)tI * DD + e] = tanhf(a);
      }
    }
    __threadfence();
    grid.sync();
  }
}

// ---------------------------------------------------------------------------
extern "C" void kernel_launch(void* const* d_in, const int* in_sizes, int n_in,
                              void* d_out, int out_size, void* d_ws, size_t ws_size,
                              hipStream_t stream) {
  const int* heads = (const int*)d_in[0];
  const int* tails = (const int*)d_in[1];
  const float* times = (const float*)d_in[2];
  float* node_rep    = (float*)d_in[3];
  float* cell_head   = (float*)d_in[4];
  float* hidden_head = (float*)d_in[5];
  float* cell_tail   = (float*)d_in[6];
  float* hidden_tail = (float*)d_in[7];
  const float* Weh1 = (const float*)d_in[8];
  const float* Weh2 = (const float*)d_in[9];
  const float* beh  = (const float*)d_in[10];
  const float* Wet1 = (const float*)d_in[11];
  const float* Wet2 = (const float*)d_in[12];
  const float* bet  = (const float*)d_in[13];
  const float* Wxh  = (const float*)d_in[14];
  const float* Whh  = (const float*)d_in[15];
  const float* bh   = (const float*)d_in[16];
  const float* Wdh  = (const float*)d_in[17];
  const float* bdh  = (const float*)d_in[18];
  const float* Wxt  = (const float*)d_in[19];
  const float* Wht  = (const float*)d_in[20];
  const float* bt   = (const float*)d_in[21];
  const float* Wdt  = (const float*)d_in[22];
  const float* bdt  = (const float*)d_in[23];
  const float* Wc1  = (const float*)d_in[24];
  const float* Wc2  = (const float*)d_in[25];

  const int S = in_sizes[0];
  const int N = in_sizes[3] / DD;

  char* ws = (char*)d_ws;
  float* rt = (float*)ws;
  size_t rtBytes = (((size_t)N * 4) + 511) & ~(size_t)511;
  int* order     = (int*)(ws + rtBytes);
  int* level_off = order + SMAX;
  int* n_levels  = level_off + SMAX + 1;
  int* ph        = n_levels + 64;          // padding for alignment
  int* pt        = ph + SMAX;

  hipMemsetAsync(rt, 0, (size_t)N * 4, stream);
  pred_kernel<<<S, 64, 0, stream>>>(heads, tails, S, ph, pt);
  finalize_kernel<<<1, 1024, 0, stream>>>(S, ph, pt, order, level_off, n_levels);

  PParams p;
  p.heads = heads; p.tails = tails; p.times = times;
  p.node_rep = node_rep; p.cell_head = cell_head; p.hidden_head = hidden_head;
  p.cell_tail = cell_tail; p.hidden_tail = hidden_tail;
  p.Weh1 = Weh1; p.Weh2 = Weh2; p.beh = beh;
  p.Wet1 = Wet1; p.Wet2 = Wet2; p.bet = bet;
  p.Wxh = Wxh; p.Whh = Whh; p.bh = bh; p.Wdh = Wdh; p.bdh = bdh;
  p.Wxt = Wxt; p.Wht = Wht; p.bt = bt; p.Wdt = Wdt; p.bdt = bdt;
  p.Wc1 = Wc1; p.Wc2 = Wc2;
  p.out = (float*)d_out; p.rt = rt;
  p.order = order; p.level_off = level_off; p.n_levels = n_levels;
  p.S = S;

  void* args[] = { (void*)&p };

  // Coop grid sizing: ask the runtime what it will accept instead of
  // hand-computing capacity (R2 lesson: 1024 hard-coded was rejected ->
  // silent zero output). These are pure host-side queries, graph-capture safe.
  int dev = 0; hipGetDevice(&dev);
  int nCU = 0;
  hipDeviceGetAttribute(&nCU, hipDeviceAttributeMultiprocessorCount, dev);
  if (nCU <= 0) nCU = 256;
  int maxBlkPerCU = 0;
  hipOccupancyMaxActiveBlocksPerMultiprocessor(&maxBlkPerCU, process_kernel, 256, 0);
  if (maxBlkPerCU < 1) maxBlkPerCU = 1;
  long long cap = (long long)nCU * (long long)maxBlkPerCU;
  int grid = (int)(cap < NBLK_MAX ? cap : NBLK_MAX);
  if (grid < 1) grid = nCU;

  hipError_t err = hipLaunchCooperativeKernel(process_kernel, dim3(grid), dim3(256),
                                              args, 0, stream);
  if (err != hipSuccess && grid > 512) {
    err = hipLaunchCooperativeKernel(process_kernel, dim3(512), dim3(256), args, 0, stream);
  }
  if (err != hipSuccess && grid > 256) {
    err = hipLaunchCooperativeKernel(process_kernel, dim3(256), dim3(256), args, 0, stream);
  }
}